// Round 12
// baseline (81.121 us; speedup 1.0000x reference)
//
#include <hip/hip_runtime.h>

#define TOKENS 16384
#define EMB 4096
#define NEXP 64
#define BK 64

typedef __attribute__((ext_vector_type(8))) short short8;
typedef __attribute__((ext_vector_type(4))) float f32x4;
typedef __attribute__((ext_vector_type(4))) unsigned short ush4;

#define WP_USHORTS (3 * NEXP * EMB)        // 1.5 MB bf16 W-planes (L2-resident)
#define WP_FLOATS  (WP_USHORTS / 2)

// async global->LDS, 16B/lane; dest = wave-uniform base + lane*16
__device__ __forceinline__ void gl_lds16(const void* g, void* lds) {
    __builtin_amdgcn_global_load_lds(
        (const __attribute__((address_space(1))) void*)g,
        (__attribute__((address_space(3))) void*)lds, 16, 0, 0);
}

// fp32 -> 3x bf16, scalar (W prep): hi RN, mid/lo trunc (R7-R11 exact).
__device__ __forceinline__ void split3(float x, unsigned short& h,
                                       unsigned short& m, unsigned short& l) {
    unsigned u = __float_as_uint(x);
    unsigned r = u + 0x7FFFu + ((u >> 16) & 1u);
    float hF = __uint_as_float(r & 0xFFFF0000u);
    h = (unsigned short)(r >> 16);
    float r1 = x - hF;
    unsigned u1 = __float_as_uint(r1);
    float mF = __uint_as_float(u1 & 0xFFFF0000u);
    m = (unsigned short)(u1 >> 16);
    float r2 = r1 - mF;
    l = (unsigned short)(__float_as_uint(r2) >> 16);
}

// pair-wise split producing packed bf16 words directly (identical planes to
// split3: RN hi, trunc mid/lo; just cheaper packing via v_perm_b32).
// word = hi16(elem1)<<16 | hi16(elem0)  (short8 word w = lanes {2w,2w+1}).
__device__ __forceinline__ void split3_pair(float x0, float x1,
        unsigned& hw, unsigned& mw, unsigned& lw) {
    unsigned u0 = __float_as_uint(x0), u1 = __float_as_uint(x1);
    unsigned r0 = u0 + 0x7FFFu + ((u0 >> 16) & 1u);
    unsigned r1 = u1 + 0x7FFFu + ((u1 >> 16) & 1u);
    hw = __builtin_amdgcn_perm(r1, r0, 0x07060302u);
    float s0 = x0 - __uint_as_float(r0 & 0xFFFF0000u);
    float s1 = x1 - __uint_as_float(r1 & 0xFFFF0000u);
    unsigned v0 = __float_as_uint(s0), v1 = __float_as_uint(s1);
    mw = __builtin_amdgcn_perm(v1, v0, 0x07060302u);
    float t0 = s0 - __uint_as_float(v0 & 0xFFFF0000u);
    float t1 = s1 - __uint_as_float(v1 & 0xFFFF0000u);
    lw = __builtin_amdgcn_perm(__float_as_uint(t1), __float_as_uint(t0), 0x07060302u);
}

// 8 floats (one k-octet pair) -> three short8 MFMA fragments
__device__ __forceinline__ void build_frags(const float4& a0, const float4& a1,
        short8& H, short8& M, short8& L) {
    union { short8 v; unsigned u[4]; } h_, m_, l_;
    split3_pair(a0.x, a0.y, h_.u[0], m_.u[0], l_.u[0]);
    split3_pair(a0.z, a0.w, h_.u[1], m_.u[1], l_.u[1]);
    split3_pair(a1.x, a1.y, h_.u[2], m_.u[2], l_.u[2]);
    split3_pair(a1.z, a1.w, h_.u[3], m_.u[3], l_.u[3]);
    H = h_.v; M = m_.v; L = l_.v;
}

// prep: split W into 3 bf16 planes Wp[plane][e][k] (flat row r = plane*64+e)
__global__ __launch_bounds__(256) void split_w(const float* __restrict__ W,
                                               unsigned short* __restrict__ Wp) {
    const int i = (blockIdx.x * 256 + threadIdx.x) * 4;
    const float4 v = *reinterpret_cast<const float4*>(W + i);
    ush4 h, m, l;
#pragma unroll
    for (int e = 0; e < 4; ++e) {
        unsigned short he, me, le;
        split3(reinterpret_cast<const float*>(&v)[e], he, me, le);
        h[e] = he; m[e] = me; l[e] = le;
    }
    *reinterpret_cast<ush4*>(Wp + i) = h;
    *reinterpret_cast<ush4*>(Wp + NEXP * EMB + i) = m;
    *reinterpret_cast<ush4*>(Wp + 2 * NEXP * EMB + i) = l;
}

// Main: MFMA split-3 bf16, counted-vmcnt 3-buffer pipeline (R11-proven),
// wave widened to 32 tokens x 64 experts: the two A-tiles share every B
// fragment -> LDS reads per MFMA halve (R11's top pipe, ~31 us/CU -> ~15).
// Block = 4 waves = 128 tokens, 256 thr; grid (128,S) -> 512 blocks = 2/CU.
// Per iter: [vmcnt(6); s_barrier; issue A(ks+1) (8 loads); issue stage(ks+2)
// (6 gl_lds); compute 96 MFMA from sB[buf]]. FIFO: queue after wait =
// [stage(ks+1)] (6 ops). XOR bank swizzle slot = piece ^ (row&7) via
// pre-swizzled gl_lds source (even 8-quad spread, verified). Precision
// identical to R7-R11 (absmax 0.0).
template<int S>
__global__ __launch_bounds__(256, 2) void router_mfma(
    const float* __restrict__ x, const unsigned short* __restrict__ Wp,
    float* __restrict__ part)
{
    constexpr int KPER = EMB / S;
    constexpr int NCH  = KPER / BK;

    __shared__ unsigned short sB[3][192][BK];   // 72 KB

    const int t  = threadIdx.x;
    const int w  = t >> 6;     // wave 0..3
    const int l  = t & 63;
    const int lr = l & 15;     // A token-row / B expert-col
    const int lo = l >> 4;     // k-octet selector
    const int tok0 = blockIdx.x * 128 + w * 32;
    const int kb   = blockIdx.y * KPER;

    const float* ax[2];
    ax[0] = x + (size_t)(tok0 + lr) * EMB + kb + lo * 8;
    ax[1] = x + (size_t)(tok0 + 16 + lr) * EMB + kb + lo * 8;

    // B staging: wave w stages rows 48w..48w+47 (6 gl_lds x 8 rows);
    // lane l -> row +(l>>3), dest slot l&7, SOURCE piece (l&7)^(row&7)
    const unsigned short* gb[6];
#pragma unroll
    for (int p = 0; p < 6; ++p)
        gb[p] = Wp + (size_t)(48 * w + 8 * p + (l >> 3)) * EMB + kb
              + 8 * ((l & 7) ^ ((l >> 3) & 7));

    f32x4 accH[2][4], accL[2][4];
#pragma unroll
    for (int ti = 0; ti < 2; ++ti)
#pragma unroll
        for (int et = 0; et < 4; ++et) {
            accH[ti][et] = (f32x4){0.f, 0.f, 0.f, 0.f};
            accL[ti][et] = (f32x4){0.f, 0.f, 0.f, 0.f};
        }

    // prologue: queue = [stage(0)(6), A(0)(8), stage(1)(6)]
    float4 ac[2][2][2], an[2][2][2];
#pragma unroll
    for (int p = 0; p < 6; ++p)
        gl_lds16(gb[p], &sB[0][48 * w + 8 * p][0]);
#pragma unroll
    for (int ti = 0; ti < 2; ++ti)
#pragma unroll
        for (int h = 0; h < 2; ++h) {
            ac[ti][h][0] = *reinterpret_cast<const float4*>(ax[ti] + 32 * h);
            ac[ti][h][1] = *reinterpret_cast<const float4*>(ax[ti] + 32 * h + 4);
        }
#pragma unroll
    for (int p = 0; p < 6; ++p)
        gl_lds16(gb[p] + BK, &sB[1][48 * w + 8 * p][0]);

    int buf = 0;
#pragma unroll 1
    for (int ks = 0; ks < NCH; ++ks) {
        // retire stage(ks)+A(ks); leave stage(ks+1) (6 ops) in flight
        asm volatile("s_waitcnt vmcnt(6)" ::: "memory");
        __builtin_amdgcn_s_barrier();

        if (ks + 1 < NCH) {
#pragma unroll
            for (int ti = 0; ti < 2; ++ti)
#pragma unroll
                for (int h = 0; h < 2; ++h) {
                    an[ti][h][0] = *reinterpret_cast<const float4*>(
                        ax[ti] + (ks + 1) * BK + 32 * h);
                    an[ti][h][1] = *reinterpret_cast<const float4*>(
                        ax[ti] + (ks + 1) * BK + 32 * h + 4);
                }
        }
        if (ks + 2 < NCH) {
            const int sb = (buf == 0) ? 2 : buf - 1;   // (ks+2)%3
#pragma unroll
            for (int p = 0; p < 6; ++p)
                gl_lds16(gb[p] + (ks + 2) * BK, &sB[sb][48 * w + 8 * p][0]);
        }
        __builtin_amdgcn_sched_barrier(0);   // pin issues before compute

#pragma unroll
        for (int h = 0; h < 2; ++h) {
            short8 aH0, aM0, aL0, aH1, aM1, aL1;
            build_frags(ac[0][h][0], ac[0][h][1], aH0, aM0, aL0);
            build_frags(ac[1][h][0], ac[1][h][1], aH1, aM1, aL1);
            const int sw = ((4 * h + lo) ^ (lr & 7)) * 8;
#pragma unroll
            for (int et = 0; et < 4; ++et) {
                const unsigned short* bp = &sB[buf][et * 16 + lr][sw];
                const short8 bH = *reinterpret_cast<const short8*>(bp);
                const short8 bM = *reinterpret_cast<const short8*>(bp + 64 * BK);
                const short8 bL = *reinterpret_cast<const short8*>(bp + 128 * BK);
                accH[0][et] = __builtin_amdgcn_mfma_f32_16x16x32_bf16(aH0, bH, accH[0][et], 0, 0, 0);
                accL[0][et] = __builtin_amdgcn_mfma_f32_16x16x32_bf16(aH0, bM, accL[0][et], 0, 0, 0);
                accL[0][et] = __builtin_amdgcn_mfma_f32_16x16x32_bf16(aM0, bH, accL[0][et], 0, 0, 0);
                accL[0][et] = __builtin_amdgcn_mfma_f32_16x16x32_bf16(aM0, bM, accL[0][et], 0, 0, 0);
                accL[0][et] = __builtin_amdgcn_mfma_f32_16x16x32_bf16(aH0, bL, accL[0][et], 0, 0, 0);
                accL[0][et] = __builtin_amdgcn_mfma_f32_16x16x32_bf16(aL0, bH, accL[0][et], 0, 0, 0);
                accH[1][et] = __builtin_amdgcn_mfma_f32_16x16x32_bf16(aH1, bH, accH[1][et], 0, 0, 0);
                accL[1][et] = __builtin_amdgcn_mfma_f32_16x16x32_bf16(aH1, bM, accL[1][et], 0, 0, 0);
                accL[1][et] = __builtin_amdgcn_mfma_f32_16x16x32_bf16(aM1, bH, accL[1][et], 0, 0, 0);
                accL[1][et] = __builtin_amdgcn_mfma_f32_16x16x32_bf16(aM1, bM, accL[1][et], 0, 0, 0);
                accL[1][et] = __builtin_amdgcn_mfma_f32_16x16x32_bf16(aH1, bL, accL[1][et], 0, 0, 0);
                accL[1][et] = __builtin_amdgcn_mfma_f32_16x16x32_bf16(aL1, bH, accL[1][et], 0, 0, 0);
            }
        }
#pragma unroll
        for (int ti = 0; ti < 2; ++ti)
#pragma unroll
            for (int h = 0; h < 2; ++h) {
                ac[ti][h][0] = an[ti][h][0];
                ac[ti][h][1] = an[ti][h][1];
            }
        buf = (buf == 2) ? 0 : buf + 1;
    }

    // epilogue: per-wave transpose in LDS aliased onto sB (stride 33 pads)
    __syncthreads();   // all waves done reading sB before overwrite
    float* sled = reinterpret_cast<float*>(&sB[0][0][0]) + w * 2112; // 64*33
#pragma unroll
    for (int ti = 0; ti < 2; ++ti)
#pragma unroll
        for (int et = 0; et < 4; ++et)
#pragma unroll
            for (int j = 0; j < 4; ++j)
                sled[(et * 16 + lr) * 33 + ti * 16 + lo * 4 + j]
                    = accH[ti][et][j] + accL[ti][et][j];
    // own-wave RAW through LDS: compiler inserts lgkmcnt (conservative alias)
#pragma unroll
    for (int r = 0; r < 32; ++r) {
        const int e = 2 * r + (l >> 5);
        part[(size_t)(blockIdx.y * NEXP + e) * TOKENS + tok0 + (l & 31)]
            = sled[e * 33 + (l & 31)];
    }
}

// combine splits in fp64 + bias, top-2, softmax (R6-R11 proven).
template<int S>
__global__ __launch_bounds__(256) void reduce_topk(
    const float* __restrict__ part, const float* __restrict__ b,
    float* __restrict__ out)
{
    __shared__ double sv[64][4][2];
    __shared__ int    si[64][4][2];
    const int t    = threadIdx.x;
    const int p4   = t & 3;
    const int slot = t >> 2;
    const int tok  = blockIdx.x * 64 + slot;

    double v[16];
#pragma unroll
    for (int j = 0; j < 16; ++j) v[j] = 0.0;
    for (int s = 0; s < S; ++s)
#pragma unroll
        for (int j = 0; j < 16; ++j)
            v[j] += (double)part[(size_t)((s << 6) + (p4 << 4) + j) * TOKENS + tok];
#pragma unroll
    for (int j = 0; j < 16; ++j) v[j] += (double)b[(p4 << 4) + j];

    double v1 = -1e300, v2 = -1e300; int i1 = 0, i2 = 0;
#pragma unroll
    for (int j = 0; j < 16; ++j) {
        const int e = (p4 << 4) + j;
        if (v[j] > v1)      { v2 = v1; i2 = i1; v1 = v[j]; i1 = e; }
        else if (v[j] > v2) { v2 = v[j]; i2 = e; }
    }
    sv[slot][p4][0] = v1; sv[slot][p4][1] = v2;
    si[slot][p4][0] = i1; si[slot][p4][1] = i2;
    __syncthreads();

    if (p4 == 0) {
        double m1 = -1e300, m2 = -1e300; int j1 = 0, j2 = 0;
#pragma unroll
        for (int p = 0; p < 4; ++p)   // ascending parts: ties keep lowest idx
#pragma unroll
            for (int r = 0; r < 2; ++r) {
                const double vv = sv[slot][p][r]; const int ii = si[slot][p][r];
                if (vv > m1)      { m2 = m1; j2 = j1; m1 = vv; j1 = ii; }
                else if (vv > m2) { m2 = vv; j2 = ii; }
            }
        const float e2  = expf((float)(m2 - m1));   // <= 1
        const float inv = 1.0f / (1.0f + e2);
        out[2 * tok]     = (float)j1;
        out[2 * tok + 1] = (float)j2;
        out[2 * TOKENS + 2 * tok]     = inv;
        out[2 * TOKENS + 2 * tok + 1] = e2 * inv;
    }
}

extern "C" void kernel_launch(void* const* d_in, const int* in_sizes, int n_in,
                              void* d_out, int out_size, void* d_ws, size_t ws_size,
                              hipStream_t stream) {
    const float* x = (const float*)d_in[0];
    const float* W = (const float*)d_in[1];
    const float* b = (const float*)d_in[2];
    float* out = (float*)d_out;
    unsigned short* Wp = (unsigned short*)d_ws;
    float* part = (float*)d_ws + WP_FLOATS;

    split_w<<<dim3(NEXP * EMB / 1024), dim3(256), 0, stream>>>(W, Wp);

    const size_t base = (size_t)WP_FLOATS * 4;
    const size_t per  = (size_t)NEXP * TOKENS * 4;   // 4.19 MB / split
    if (ws_size >= base + 4 * per) {         // 18.3 MB (proven) -> 512 blocks
        router_mfma<4><<<dim3(TOKENS / 128, 4), dim3(256), 0, stream>>>(x, Wp, part);
        reduce_topk<4><<<dim3(TOKENS / 64), dim3(256), 0, stream>>>(part, b, out);
    } else if (ws_size >= base + 2 * per) {
        router_mfma<2><<<dim3(TOKENS / 128, 2), dim3(256), 0, stream>>>(x, Wp, part);
        reduce_topk<2><<<dim3(TOKENS / 64), dim3(256), 0, stream>>>(part, b, out);
    } else {
        router_mfma<1><<<dim3(TOKENS / 128, 1), dim3(256), 0, stream>>>(x, Wp, part);
        reduce_topk<1><<<dim3(TOKENS / 64), dim3(256), 0, stream>>>(part, b, out);
    }
}